// Round 3
// baseline (231.223 us; speedup 1.0000x reference)
//
#include <hip/hip_runtime.h>
#include <hip/hip_bf16.h>
#include <cstddef>

typedef __attribute__((ext_vector_type(8))) short short8;   // 8 x bf16 (4 VGPRs)
typedef __attribute__((ext_vector_type(4))) float f32x4;    // MFMA accumulator

// ---------------------------------------------------------------------------
// helpers
// ---------------------------------------------------------------------------
__device__ __forceinline__ unsigned short f2bf(float f) {   // RNE f32 -> bf16
    unsigned int u = __float_as_uint(f);
    u = (u + 0x7FFFu + ((u >> 16) & 1u)) >> 16;
    return (unsigned short)u;
}
__device__ __forceinline__ float bf2f(unsigned short h) {
    return __uint_as_float(((unsigned int)h) << 16);
}
__device__ __forceinline__ float silu_f(float v)  { return v / (1.f + expf(-v)); }

// ws layout (bf16 elements)
#define O_X     0
#define O_WIP   (262144)                 // x: 512*512
#define O_WXP   (O_WIP + 1048576)        // in_proj_w: 2048*512
#define O_WDT   (O_WXP + 294912)         // x_proj_w: 288*1024
#define O_WOUT  (O_WDT + 32768)          // dt_proj_w: 1024*32
#define O_WFC1  (O_WOUT + 524288)        // out_proj_w: 512*1024
// fc1_w: 256*512 = 131072

// ---------------------------------------------------------------------------
// Kernel 1: cast x + 5 weight matrices f32 -> bf16 into ws.
// ---------------------------------------------------------------------------
__device__ __forceinline__ void cvt_seg(const float* __restrict__ s,
                                        unsigned short* __restrict__ d,
                                        int n, int tid, int np)
{
    for (int i = tid * 4; i < n; i += np * 4) {
        float4 v = *reinterpret_cast<const float4*>(s + i);
        ushort4 o;
        o.x = f2bf(v.x); o.y = f2bf(v.y); o.z = f2bf(v.z); o.w = f2bf(v.w);
        *reinterpret_cast<ushort4*>(d + i) = o;
    }
}

__global__ __launch_bounds__(256) void k_convert(
    const float* __restrict__ x,   const float* __restrict__ wip,
    const float* __restrict__ wxp, const float* __restrict__ wdt,
    const float* __restrict__ wout,const float* __restrict__ wfc1,
    unsigned short* __restrict__ dst)
{
    const int tid = blockIdx.x * blockDim.x + threadIdx.x;
    const int np  = gridDim.x * blockDim.x;
    cvt_seg(x,    dst + O_X,    262144,  tid, np);
    cvt_seg(wip,  dst + O_WIP,  1048576, tid, np);
    cvt_seg(wxp,  dst + O_WXP,  294912,  tid, np);
    cvt_seg(wdt,  dst + O_WDT,  32768,   tid, np);
    cvt_seg(wout, dst + O_WOUT, 524288,  tid, np);
    cvt_seg(wfc1, dst + O_WFC1, 131072,  tid, np);
}

// ---------------------------------------------------------------------------
// Kernel 2: fully fused network. One block = 16 batch rows through all stages.
// 512 threads = 8 waves. MFMA 16x16x32 bf16; fragment layout (m89-verified):
//   A: row = lane&15, k = (lane>>4)*8 + j   (8 contiguous K elems, 16B load)
//   B: col(n) = lane&15, k = (lane>>4)*8 + j (weights row-major N x K: same)
//   C/D: col = lane&15, row = (lane>>4)*4 + reg
// LDS region A (33,024B): xin(bf16,16x1032) -> y(bf16) -> h1(f32,16x260)
// LDS region C (16,640B): xdbl(bf16,16x328) -> mout(bf16,16x520)
// Row strides chosen so stride % 128B == 16 (2-way bank alias = free).
// xin and silu(z) fragments are ALSO kept in registers (same wave owns the
// matching y tile in stage 3 -> no LDS needed for sz at all).
// ---------------------------------------------------------------------------
__global__ __launch_bounds__(512, 2) void k_fused(
    const unsigned short* __restrict__ wsb,
    const float* __restrict__ cw,   const float* __restrict__ cb,
    const float* __restrict__ dtb,  const float* __restrict__ Dv,
    const float* __restrict__ bfc1, const float* __restrict__ wfc5,
    const float* __restrict__ bfc5, float* __restrict__ out)
{
    __shared__ __align__(16) unsigned short A_s[16 * 1032];
    __shared__ __align__(16) unsigned short C_s[16 * 520];
    __shared__ float bcp_s[16][17];
    __shared__ float bc_s[16];

    const unsigned short* xbf  = wsb + O_X;
    const unsigned short* wip  = wsb + O_WIP;
    const unsigned short* wxp  = wsb + O_WXP;
    const unsigned short* wdt  = wsb + O_WDT;
    const unsigned short* wout = wsb + O_WOUT;
    const unsigned short* wfc1 = wsb + O_WFC1;

    const int tid  = threadIdx.x;
    const int w    = tid >> 6;        // wave 0..7
    const int lane = tid & 63;
    const int l15  = lane & 15;
    const int g    = lane >> 4;       // k-group 0..3
    const int m0   = blockIdx.x * 16; // this block's batch rows

    const f32x4 zero4 = {0.f, 0.f, 0.f, 0.f};
    f32x4 xin_r[8], sz_r[8];          // per-wave xin / silu(z) fragments

    // ================= stage 1: xz = x @ in_proj_w^T (K=512, N=2048) ========
    // pass 0: n in [0,1024)  -> xin = silu(conv_b + conv_w[:,1]*xz)
    // pass 1: n in [1024,2048)-> sz = silu(z), registers only
    {
        const unsigned short* xrow = xbf + (size_t)(m0 + l15) * 512 + g * 8;
        for (int pass = 0; pass < 2; ++pass) {
            f32x4 acc[8];
#pragma unroll
            for (int t = 0; t < 8; ++t) acc[t] = zero4;
            for (int k0 = 0; k0 < 512; k0 += 32) {
                short8 a = *reinterpret_cast<const short8*>(xrow + k0);
#pragma unroll
                for (int t = 0; t < 8; ++t) {
                    int n0 = pass * 1024 + (w * 8 + t) * 16;
                    short8 b = *reinterpret_cast<const short8*>(
                        wip + (size_t)(n0 + l15) * 512 + k0 + g * 8);
                    acc[t] = __builtin_amdgcn_mfma_f32_16x16x32_bf16(a, b, acc[t], 0, 0, 0);
                }
            }
#pragma unroll
            for (int t = 0; t < 8; ++t) {
                int n = (w * 8 + t) * 16 + l15;   // 0..1023 (local col)
                if (pass == 0) {
                    float cwv = cw[2 * n + 1], cbv = cb[n];
#pragma unroll
                    for (int i = 0; i < 4; ++i) {
                        float v = silu_f(cbv + cwv * acc[t][i]);
                        xin_r[t][i] = v;
                        A_s[(g * 4 + i) * 1032 + n] = f2bf(v);
                    }
                } else {
#pragma unroll
                    for (int i = 0; i < 4; ++i) sz_r[t][i] = silu_f(acc[t][i]);
                }
            }
        }
    }
    __syncthreads();   // B0: xin in A_s complete

    // ================= stage 2: xdbl = xin @ x_proj_w^T (K=1024, N=288) =====
    {
        f32x4 acc[3] = {zero4, zero4, zero4};
        for (int k0 = 0; k0 < 1024; k0 += 32) {
            short8 a = *reinterpret_cast<const short8*>(&A_s[l15 * 1032 + k0 + g * 8]);
#pragma unroll
            for (int i = 0; i < 3; ++i) {
                int t = w + 8 * i;
                if (t < 18) {
                    short8 b = *reinterpret_cast<const short8*>(
                        wxp + (size_t)(t * 16 + l15) * 1024 + k0 + g * 8);
                    acc[i] = __builtin_amdgcn_mfma_f32_16x16x32_bf16(a, b, acc[i], 0, 0, 0);
                }
            }
        }
#pragma unroll
        for (int i = 0; i < 3; ++i) {
            int t = w + 8 * i;
            if (t < 18) {
                int n = t * 16 + l15;             // 0..287
#pragma unroll
                for (int j = 0; j < 4; ++j)
                    C_s[(g * 4 + j) * 328 + n] = f2bf(acc[i][j]);
            }
        }
    }
    __syncthreads();   // B1: xdbl in C_s complete

    // ===== stage 3 prologue: dt A-fragment + bc[r] = sum_s Bm[r,s]*Cm[r,s] ==
    short8 a3 = *reinterpret_cast<const short8*>(&C_s[l15 * 328 + g * 8]); // cols 0..31
    if (tid < 256) {
        int rr = tid >> 4, p = tid & 15;
        const unsigned short* row = &C_s[rr * 328];
        float s = 0.f;
#pragma unroll
        for (int q = 0; q < 8; ++q)
            s += bf2f(row[32 + p * 8 + q]) * bf2f(row[160 + p * 8 + q]);
        bcp_s[rr][p] = s;
    }
    __syncthreads();   // B2
    if (tid < 16) {
        float s = 0.f;
#pragma unroll
        for (int p = 0; p < 16; ++p) s += bcp_s[tid][p];
        bc_s[tid] = s;
    }
    __syncthreads();   // B3: bc ready; all C_s/A_s reads of stages 1-2 done

    // ===== stage 3: dt = softplus(xdbl[:, :32] @ dt_proj_w^T + b) (K=32) ====
    //   y = xin * (dt*bc + D) * silu(z)   -> overwrite region A with y (bf16)
#pragma unroll
    for (int t = 0; t < 8; ++t) {
        int n = (w * 8 + t) * 16 + l15;           // 0..1023, SAME tile as xin_r[t]
        short8 b = *reinterpret_cast<const short8*>(wdt + (size_t)n * 32 + g * 8);
        f32x4 acc = __builtin_amdgcn_mfma_f32_16x16x32_bf16(a3, b, zero4, 0, 0, 0);
        float dtbv = dtb[n], Dvv = Dv[n];
#pragma unroll
        for (int i = 0; i < 4; ++i) {
            int r = g * 4 + i;
            float dtv = acc[i] + dtbv;
            dtv = (dtv > 20.f) ? dtv : log1pf(expf(dtv));     // softplus
            float yv = xin_r[t][i] * (dtv * bc_s[r] + Dvv) * sz_r[t][i];
            A_s[r * 1032 + n] = f2bf(yv);
        }
    }
    __syncthreads();   // B4: y in A_s complete

    // ================= stage 4: mout = y @ out_proj_w^T (K=1024, N=512) =====
    {
        f32x4 acc[4] = {zero4, zero4, zero4, zero4};
        for (int k0 = 0; k0 < 1024; k0 += 32) {
            short8 a = *reinterpret_cast<const short8*>(&A_s[l15 * 1032 + k0 + g * 8]);
#pragma unroll
            for (int i = 0; i < 4; ++i) {
                int n0 = (w + 8 * i) * 16;
                short8 b = *reinterpret_cast<const short8*>(
                    wout + (size_t)(n0 + l15) * 1024 + k0 + g * 8);
                acc[i] = __builtin_amdgcn_mfma_f32_16x16x32_bf16(a, b, acc[i], 0, 0, 0);
            }
        }
#pragma unroll
        for (int i = 0; i < 4; ++i) {
            int n = (w + 8 * i) * 16 + l15;       // 0..511
#pragma unroll
            for (int j = 0; j < 4; ++j)
                C_s[(g * 4 + j) * 520 + n] = f2bf(acc[i][j]);
        }
    }
    __syncthreads();   // B5: mout in C_s complete; all y reads done

    // ================= stage 5: h1 = mout @ fc1_w^T (K=512, N=256) ==========
    {
        f32x4 acc[2] = {zero4, zero4};
        for (int k0 = 0; k0 < 512; k0 += 32) {
            short8 a = *reinterpret_cast<const short8*>(&C_s[l15 * 520 + k0 + g * 8]);
#pragma unroll
            for (int i = 0; i < 2; ++i) {
                int n0 = (w + 8 * i) * 16;
                short8 b = *reinterpret_cast<const short8*>(
                    wfc1 + (size_t)(n0 + l15) * 512 + k0 + g * 8);
                acc[i] = __builtin_amdgcn_mfma_f32_16x16x32_bf16(a, b, acc[i], 0, 0, 0);
            }
        }
        float* h1 = reinterpret_cast<float*>(A_s);   // region A reused, f32 [16][260]
#pragma unroll
        for (int i = 0; i < 2; ++i) {
            int n = (w + 8 * i) * 16 + l15;       // 0..255
#pragma unroll
            for (int j = 0; j < 4; ++j)
                h1[(g * 4 + j) * 260 + n] = acc[i][j];
        }
    }
    __syncthreads();   // B6: h1 complete

    // ================= stage 6: head (leaky -> fc5 dot -> sigmoid) ==========
    {
        const float* h1 = reinterpret_cast<const float*>(A_s);
        float4 wv = *reinterpret_cast<const float4*>(&wfc5[lane * 4]);
        float4 bv = *reinterpret_cast<const float4*>(&bfc1[lane * 4]);
#pragma unroll
        for (int rr = 0; rr < 2; ++rr) {
            int r = w * 2 + rr;                   // 0..15
            float4 h = *reinterpret_cast<const float4*>(&h1[r * 260 + lane * 4]);
            float v0 = h.x + bv.x, v1 = h.y + bv.y, v2 = h.z + bv.z, v3 = h.w + bv.w;
            v0 = v0 >= 0.f ? v0 : 0.1f * v0;
            v1 = v1 >= 0.f ? v1 : 0.1f * v1;
            v2 = v2 >= 0.f ? v2 : 0.1f * v2;
            v3 = v3 >= 0.f ? v3 : 0.1f * v3;
            float s = v0 * wv.x + v1 * wv.y + v2 * wv.z + v3 * wv.w;
#pragma unroll
            for (int off = 32; off > 0; off >>= 1) s += __shfl_xor(s, off, 64);
            if (lane == 0) out[m0 + r] = 1.f / (1.f + expf(-(s + bfc5[0])));
        }
    }
}

// ---------------------------------------------------------------------------
extern "C" void kernel_launch(void* const* d_in, const int* in_sizes, int n_in,
                              void* d_out, int out_size, void* d_ws, size_t ws_size,
                              hipStream_t stream)
{
    const float* x    = (const float*)d_in[0];
    const float* wip  = (const float*)d_in[1];
    const float* cw   = (const float*)d_in[2];
    const float* cb   = (const float*)d_in[3];
    const float* wxp  = (const float*)d_in[4];
    const float* wdt  = (const float*)d_in[5];
    const float* bdt  = (const float*)d_in[6];
    // d_in[7] = A_log: unused — h0 == 0 at L==1 so dA never contributes.
    const float* Dv   = (const float*)d_in[8];
    const float* wout = (const float*)d_in[9];
    const float* wfc1 = (const float*)d_in[10];
    const float* bfc1 = (const float*)d_in[11];
    const float* wfc5 = (const float*)d_in[12];
    const float* bfc5 = (const float*)d_in[13];
    float* out = (float*)d_out;

    unsigned short* wsb = (unsigned short*)d_ws;   // bf16 staging (~4.6 MB)

    k_convert<<<1024, 256, 0, stream>>>(x, wip, wxp, wdt, wout, wfc1, wsb);
    k_fused  <<<32,   512, 0, stream>>>(wsb, cw, cb, bdt, Dv, bfc1, wfc5, bfc5, out);
}

// Round 4
// 157.124 us; speedup vs baseline: 1.4716x; 1.4716x over previous
//
#include <hip/hip_runtime.h>
#include <hip/hip_bf16.h>
#include <cstddef>

typedef __attribute__((ext_vector_type(8))) short short8;   // 8 x bf16
typedef __attribute__((ext_vector_type(4))) float f32x4;    // MFMA accumulator

#define MFMA16(a, b, c) __builtin_amdgcn_mfma_f32_16x16x32_bf16((a), (b), (c), 0, 0, 0)

__device__ __forceinline__ unsigned short f2bf(float f) {   // RNE f32 -> bf16
    unsigned int u = __float_as_uint(f);
    u = (u + 0x7FFFu + ((u >> 16) & 1u)) >> 16;
    return (unsigned short)u;
}
__device__ __forceinline__ float bf2f(unsigned short h) {
    return __uint_as_float(((unsigned int)h) << 16);
}
__device__ __forceinline__ float silu_f(float v) { return v / (1.f + expf(-v)); }

// ws layout (bf16 element offsets, all multiples of 8 -> 16B aligned)
enum : size_t {
    O_X    = 0,                        // 512 x 512
    O_WIP  = O_X    + 512 * 512,       // 2048 x 512
    O_WXP  = O_WIP  + 2048 * 512,      // 288 x 1024
    O_WDT  = O_WXP  + 288 * 1024,      // 1024 x 32
    O_WOUT = O_WDT  + 1024 * 32,       // 512 x 1024
    O_WFC1 = O_WOUT + 512 * 1024,      // 256 x 512
    O_XIN  = O_WFC1 + 256 * 512,       // 512 x 1024 activations (bf16)
    O_SZ   = O_XIN  + 512 * 1024,      // 512 x 1024
    O_XDBL = O_SZ   + 512 * 1024,      // 512 x 288
    O_Y    = O_XDBL + 512 * 288,       // 512 x 1024
    O_MOUT = O_Y    + 512 * 1024,      // 512 x 512    (total ~8.6 MB)
};

// ---------------------------------------------------------------------------
// k_convert: cast x + 5 weight matrices f32 -> bf16 into ws.
// ---------------------------------------------------------------------------
__device__ __forceinline__ void cvt_seg(const float* __restrict__ s,
                                        unsigned short* __restrict__ d,
                                        int n, int tid, int np)
{
    for (int i = tid * 4; i < n; i += np * 4) {
        float4 v = *reinterpret_cast<const float4*>(s + i);
        ushort4 o;
        o.x = f2bf(v.x); o.y = f2bf(v.y); o.z = f2bf(v.z); o.w = f2bf(v.w);
        *reinterpret_cast<ushort4*>(d + i) = o;
    }
}

__global__ __launch_bounds__(256) void k_convert(
    const float* __restrict__ x,    const float* __restrict__ wip,
    const float* __restrict__ wxp,  const float* __restrict__ wdt,
    const float* __restrict__ wout, const float* __restrict__ wfc1,
    unsigned short* __restrict__ dst)
{
    const int tid = blockIdx.x * blockDim.x + threadIdx.x;
    const int np  = gridDim.x * blockDim.x;
    cvt_seg(x,    dst + O_X,    512 * 512,   tid, np);
    cvt_seg(wip,  dst + O_WIP,  2048 * 512,  tid, np);
    cvt_seg(wxp,  dst + O_WXP,  288 * 1024,  tid, np);
    cvt_seg(wdt,  dst + O_WDT,  1024 * 32,   tid, np);
    cvt_seg(wout, dst + O_WOUT, 512 * 1024,  tid, np);
    cvt_seg(wfc1, dst + O_WFC1, 256 * 512,   tid, np);
}

// ---------------------------------------------------------------------------
// Stage 1: xz = x @ in_proj_w^T (M=512, N=2048, K=512) + conv/silu epilogue.
// Grid (32 n-tiles, 8 m-tiles); block 256 thr = 4 waves; wave = 16 rows x 64
// cols. nx=32 % 8 == 0 -> all m-tiles of an n-tile land on one XCD (B reuse).
// n <  1024: xin = silu(conv_b + conv_w[:,1]*v);  n >= 1024: sz = silu(v).
// ---------------------------------------------------------------------------
__global__ __launch_bounds__(256, 2) void k_s1(
    unsigned short* __restrict__ wsb,
    const float* __restrict__ cw, const float* __restrict__ cb)
{
    const int tid = threadIdx.x;
    const int w = tid >> 6, lane = tid & 63, l15 = lane & 15, g = lane >> 4;
    const int n0 = blockIdx.x * 64;
    const int m0 = blockIdx.y * 64 + w * 16;

    const unsigned short* ab = wsb + O_X   + (size_t)(m0 + l15) * 512 + g * 8;
    const unsigned short* bb = wsb + O_WIP + (size_t)(n0 + l15) * 512 + g * 8;

    f32x4 acc[4] = {};
#pragma unroll 4
    for (int k0 = 0; k0 < 512; k0 += 32) {
        short8 a = *reinterpret_cast<const short8*>(ab + k0);
#pragma unroll
        for (int f = 0; f < 4; ++f) {
            short8 b = *reinterpret_cast<const short8*>(bb + f * 16 * 512 + k0);
            acc[f] = MFMA16(a, b, acc[f]);
        }
    }

    const bool xhalf = (n0 < 1024);
    unsigned short* dst = wsb + (xhalf ? O_XIN : O_SZ);
#pragma unroll
    for (int f = 0; f < 4; ++f) {
        int n = n0 + f * 16 + l15;                 // global col 0..2047
        int c = xhalf ? n : n - 1024;              // col in 0..1023
        float cwv = 0.f, cbv = 0.f;
        if (xhalf) { cwv = cw[2 * n + 1]; cbv = cb[n]; }
#pragma unroll
        for (int i = 0; i < 4; ++i) {
            int r = m0 + g * 4 + i;
            float v = acc[f][i];
            v = xhalf ? silu_f(cbv + cwv * v) : silu_f(v);
            dst[(size_t)r * 1024 + c] = f2bf(v);
        }
    }
}

// ---------------------------------------------------------------------------
// Stage 2: xdbl = xin @ x_proj_w^T (M=512, N=288, K=1024).
// Grid (18 n-tiles, 8 m-tiles); wave = 16 rows x 16 cols; 1 MFMA / k-step.
// ---------------------------------------------------------------------------
__global__ __launch_bounds__(256, 2) void k_s2(unsigned short* __restrict__ wsb)
{
    const int tid = threadIdx.x;
    const int w = tid >> 6, lane = tid & 63, l15 = lane & 15, g = lane >> 4;
    const int n0 = blockIdx.x * 16;
    const int m0 = blockIdx.y * 64 + w * 16;

    const unsigned short* ab = wsb + O_XIN + (size_t)(m0 + l15) * 1024 + g * 8;
    const unsigned short* bb = wsb + O_WXP + (size_t)(n0 + l15) * 1024 + g * 8;

    f32x4 acc = {};
#pragma unroll 4
    for (int k0 = 0; k0 < 1024; k0 += 32) {
        short8 a = *reinterpret_cast<const short8*>(ab + k0);
        short8 b = *reinterpret_cast<const short8*>(bb + k0);
        acc = MFMA16(a, b, acc);
    }
    unsigned short* xd = wsb + O_XDBL;
#pragma unroll
    for (int i = 0; i < 4; ++i)
        xd[(size_t)(m0 + g * 4 + i) * 288 + n0 + l15] = f2bf(acc[i]);
}

// ---------------------------------------------------------------------------
// Stage 3: dt = softplus(xdbl[:, :32] @ dt_proj_w^T + b); bc[r] = Bm.Cm;
//          y = xin * (dt*bc + D) * sz.   (M=512, N=1024, K=32)
// Grid (4 n-tiles of 256, 32 m-tiles of 16); wave = 16 rows x 64 cols.
// ---------------------------------------------------------------------------
__global__ __launch_bounds__(256, 2) void k_s3(
    unsigned short* __restrict__ wsb,
    const float* __restrict__ dtb, const float* __restrict__ Dv)
{
    __shared__ float bcp[16][17];
    __shared__ float bc_s[16];
    const int tid = threadIdx.x;
    const int w = tid >> 6, lane = tid & 63, l15 = lane & 15, g = lane >> 4;
    const int n0 = blockIdx.x * 256;
    const int m0 = blockIdx.y * 16;

    const unsigned short* xd = wsb + O_XDBL;
    {   // bc[r] = sum_s Bm[r,s]*Cm[r,s]  (cols 32..159 x 160..287 of xdbl row)
        int r = tid >> 4, p = tid & 15;
        const unsigned short* row = xd + (size_t)(m0 + r) * 288;
        float s = 0.f;
#pragma unroll
        for (int q = 0; q < 16; ++q)
            s += bf2f(row[32 + p * 16 + q]) * bf2f(row[160 + p * 16 + q]);
        bcp[r][p] = s;
    }
    // A fragment: dt_low = xdbl cols 0..31
    short8 a = *reinterpret_cast<const short8*>(xd + (size_t)(m0 + l15) * 288 + g * 8);
    __syncthreads();
    if (tid < 16) {
        float s = 0.f;
#pragma unroll
        for (int p = 0; p < 16; ++p) s += bcp[tid][p];
        bc_s[tid] = s;
    }
    __syncthreads();

    const unsigned short* wdt  = wsb + O_WDT;
    const unsigned short* xinb = wsb + O_XIN;
    const unsigned short* szb  = wsb + O_SZ;
    unsigned short* yb = wsb + O_Y;
    const f32x4 z4 = {0.f, 0.f, 0.f, 0.f};
#pragma unroll
    for (int f = 0; f < 4; ++f) {
        int n = n0 + w * 64 + f * 16 + l15;        // 0..1023
        short8 b = *reinterpret_cast<const short8*>(wdt + (size_t)n * 32 + g * 8);
        f32x4 acc = MFMA16(a, b, z4);
        float dtbv = dtb[n], Dvv = Dv[n];
#pragma unroll
        for (int i = 0; i < 4; ++i) {
            int r = m0 + g * 4 + i;
            float dtv = acc[i] + dtbv;
            dtv = (dtv > 20.f) ? dtv : log1pf(expf(dtv));   // softplus
            float yv = bf2f(xinb[(size_t)r * 1024 + n]) *
                       (dtv * bc_s[g * 4 + i] + Dvv) *
                       bf2f(szb[(size_t)r * 1024 + n]);
            yb[(size_t)r * 1024 + n] = f2bf(yv);
        }
    }
}

// ---------------------------------------------------------------------------
// Stage 4: mout = y @ out_proj_w^T (M=512, N=512, K=1024).
// Grid (8 n-tiles, 8 m-tiles); wave = 16 rows x 64 cols. nx=8 % 8 == 0.
// ---------------------------------------------------------------------------
__global__ __launch_bounds__(256, 2) void k_s4(unsigned short* __restrict__ wsb)
{
    const int tid = threadIdx.x;
    const int w = tid >> 6, lane = tid & 63, l15 = lane & 15, g = lane >> 4;
    const int n0 = blockIdx.x * 64;
    const int m0 = blockIdx.y * 64 + w * 16;

    const unsigned short* ab = wsb + O_Y    + (size_t)(m0 + l15) * 1024 + g * 8;
    const unsigned short* bb = wsb + O_WOUT + (size_t)(n0 + l15) * 1024 + g * 8;

    f32x4 acc[4] = {};
#pragma unroll 4
    for (int k0 = 0; k0 < 1024; k0 += 32) {
        short8 a = *reinterpret_cast<const short8*>(ab + k0);
#pragma unroll
        for (int f = 0; f < 4; ++f) {
            short8 b = *reinterpret_cast<const short8*>(bb + f * 16 * 1024 + k0);
            acc[f] = MFMA16(a, b, acc[f]);
        }
    }
    unsigned short* mo = wsb + O_MOUT;
#pragma unroll
    for (int f = 0; f < 4; ++f)
#pragma unroll
        for (int i = 0; i < 4; ++i)
            mo[(size_t)(m0 + g * 4 + i) * 512 + n0 + f * 16 + l15] = f2bf(acc[f][i]);
}

// ---------------------------------------------------------------------------
// Stage 5: h1 = mout @ fc1_w^T (M=512, N=256, K=512) fused with the head:
//   out[b] = sigmoid(fc5_b + sum_j fc5_w[j] * leaky(h1[b,j] + fc1_b[j])).
// Grid 32 blocks (16 rows each); wave w = cols w*64..w*64+64; LDS reduce.
// ---------------------------------------------------------------------------
__global__ __launch_bounds__(256, 2) void k_s5(
    unsigned short* __restrict__ wsb,
    const float* __restrict__ bfc1, const float* __restrict__ wfc5,
    const float* __restrict__ bfc5, float* __restrict__ out)
{
    __shared__ float red[16][72];
    const int tid = threadIdx.x;
    const int w = tid >> 6, lane = tid & 63, l15 = lane & 15, g = lane >> 4;
    const int m0 = blockIdx.x * 16;

    const unsigned short* ab = wsb + O_MOUT + (size_t)(m0 + l15) * 512 + g * 8;
    const unsigned short* bb = wsb + O_WFC1 + (size_t)(w * 64 + l15) * 512 + g * 8;

    f32x4 acc[4] = {};
#pragma unroll 4
    for (int k0 = 0; k0 < 512; k0 += 32) {
        short8 a = *reinterpret_cast<const short8*>(ab + k0);
#pragma unroll
        for (int f = 0; f < 4; ++f) {
            short8 b = *reinterpret_cast<const short8*>(bb + f * 16 * 512 + k0);
            acc[f] = MFMA16(a, b, acc[f]);
        }
    }
    float part[4] = {0.f, 0.f, 0.f, 0.f};
#pragma unroll
    for (int f = 0; f < 4; ++f) {
        int n = w * 64 + f * 16 + l15;             // 0..255
        float b1 = bfc1[n], w5 = wfc5[n];
#pragma unroll
        for (int i = 0; i < 4; ++i) {
            float v = acc[f][i] + b1;
            v = v >= 0.f ? v : 0.1f * v;           // leaky relu
            part[i] = fmaf(v, w5, part[i]);
        }
    }
#pragma unroll
    for (int i = 0; i < 4; ++i) red[g * 4 + i][w * 16 + l15] = part[i];
    __syncthreads();
    if (tid < 16) {
        float s = 0.f;
        for (int j = 0; j < 64; ++j) s += red[tid][j];
        out[m0 + tid] = 1.f / (1.f + expf(-(s + bfc5[0])));
    }
}

// ---------------------------------------------------------------------------
extern "C" void kernel_launch(void* const* d_in, const int* in_sizes, int n_in,
                              void* d_out, int out_size, void* d_ws, size_t ws_size,
                              hipStream_t stream)
{
    const float* x    = (const float*)d_in[0];
    const float* wip  = (const float*)d_in[1];
    const float* cw   = (const float*)d_in[2];
    const float* cb   = (const float*)d_in[3];
    const float* wxp  = (const float*)d_in[4];
    const float* wdt  = (const float*)d_in[5];
    const float* bdt  = (const float*)d_in[6];
    // d_in[7] = A_log: unused — h0 == 0 at L==1 so dA never contributes.
    const float* Dv   = (const float*)d_in[8];
    const float* wout = (const float*)d_in[9];
    const float* wfc1 = (const float*)d_in[10];
    const float* bfc1 = (const float*)d_in[11];
    const float* wfc5 = (const float*)d_in[12];
    const float* bfc5 = (const float*)d_in[13];
    float* out = (float*)d_out;

    unsigned short* wsb = (unsigned short*)d_ws;   // bf16 staging + activations

    k_convert<<<dim3(512),   256, 0, stream>>>(x, wip, wxp, wdt, wout, wfc1, wsb);
    k_s1     <<<dim3(32, 8), 256, 0, stream>>>(wsb, cw, cb);
    k_s2     <<<dim3(18, 8), 256, 0, stream>>>(wsb);
    k_s3     <<<dim3(4, 32), 256, 0, stream>>>(wsb, bdt, Dv);
    k_s4     <<<dim3(8, 8),  256, 0, stream>>>(wsb);
    k_s5     <<<dim3(32),    256, 0, stream>>>(wsb, bfc1, wfc5, bfc5, out);
}